// Round 1
// baseline (201.830 us; speedup 1.0000x reference)
//
#include <hip/hip_runtime.h>

#define NN    512
#define D     128      // INPUT_DIM
#define HID   256      // HIDDEN_DIM
#define REL   128      // REL_DIM
#define ODIM  64

#define TI    8
#define TJ    16
#define PAIRS 128      // TI*TJ pairs per block
#define KC    32       // k-chunk
#define AP    260      // padded row stride for A/B tiles (floats)
#define HP    36       // padded row stride for h tile
#define WP    132      // padded row stride for W2 tile
#define NBLK  2048     // (512/TI)*(512/TJ)

// ---------------- kernel A: A'[i][c] = x_i @ W1_top[:,c] + b1[c]; B[i][c] = x_i @ W1_bot[:,c]
__global__ void kA(const float* __restrict__ X, const float* __restrict__ W1,
                   const float* __restrict__ b1, float* __restrict__ Apb,
                   float* __restrict__ Bm) {
    __shared__ float Xsh[D];
    int i = blockIdx.x;
    int c = threadIdx.x;                 // 0..255
    if (c < D) Xsh[c] = X[i * D + c];
    __syncthreads();
    float a = 0.f, b = 0.f;
#pragma unroll 8
    for (int k = 0; k < D; ++k) {
        float x = Xsh[k];
        a += x * W1[k * HID + c];
        b += x * W1[(D + k) * HID + c];
    }
    Apb[i * HID + c] = a + b1[c];
    Bm[i * HID + c]  = b;
}

// ---------------- kernel B: the 17 GFLOP pair GEMM + relu + per-block pair-sum
__global__ __launch_bounds__(256, 2) void kB(const float* __restrict__ Apb,
                                             const float* __restrict__ Bm,
                                             const float* __restrict__ W2,
                                             const float* __restrict__ b2,
                                             float* __restrict__ partial) {
    __shared__ float Ash[TI * AP];
    __shared__ float Bsh[TJ * AP];
    __shared__ float hsh[PAIRS * HP];
    __shared__ float W2sh[KC * WP];
    __shared__ float redsh[16 * WP];

    int t   = threadIdx.x;
    int blk = blockIdx.x;
    int bi  = blk >> 5, bj = blk & 31;
    int i0  = bi * TI, j0 = bj * TJ;

    // stage A' rows (8 x 256 floats = 512 float4)
#pragma unroll
    for (int q = 0; q < 2; ++q) {
        int idx4 = q * 256 + t;
        int r = idx4 >> 6, c4 = idx4 & 63;
        float4 v = *(const float4*)&Apb[(i0 + r) * HID + c4 * 4];
        *(float4*)&Ash[r * AP + c4 * 4] = v;
    }
    // stage B rows (16 x 256 floats = 1024 float4)
#pragma unroll
    for (int q = 0; q < 4; ++q) {
        int idx4 = q * 256 + t;
        int r = idx4 >> 6, c4 = idx4 & 63;
        float4 v = *(const float4*)&Bm[(j0 + r) * HID + c4 * 4];
        *(float4*)&Bsh[r * AP + c4 * 4] = v;
    }

    int og = t & 15, pg = t >> 4;
    int obase = og * 8;

    float acc[8][8];
#pragma unroll
    for (int a = 0; a < 8; ++a)
#pragma unroll
        for (int b = 0; b < 8; ++b) acc[a][b] = 0.f;

    for (int kc = 0; kc < HID / KC; ++kc) {
        int k0 = kc * KC;
        __syncthreads();   // also covers Ash/Bsh staging on first iter
        // stage W2 chunk: rows k0..k0+31 x 128 (1024 float4, coalesced)
#pragma unroll
        for (int q = 0; q < 4; ++q) {
            int idx4 = q * 256 + t;
            int k = idx4 >> 5, c4 = idx4 & 31;
            float4 v = *(const float4*)&W2[(k0 + k) * REL + c4 * 4];
            *(float4*)&W2sh[k * WP + c4 * 4] = v;
        }
        // stage h chunk: h[p][k] = relu(A'[i_loc][k0+k] + B[j_loc][k0+k])
#pragma unroll
        for (int q = 0; q < 4; ++q) {
            int idx4 = q * 256 + t;
            int p = idx4 >> 3, k4 = idx4 & 7;
            int il = p >> 4, jl = p & 15;
            float4 av = *(const float4*)&Ash[il * AP + k0 + k4 * 4];
            float4 bv = *(const float4*)&Bsh[jl * AP + k0 + k4 * 4];
            float4 h;
            h.x = fmaxf(av.x + bv.x, 0.f);
            h.y = fmaxf(av.y + bv.y, 0.f);
            h.z = fmaxf(av.z + bv.z, 0.f);
            h.w = fmaxf(av.w + bv.w, 0.f);
            *(float4*)&hsh[p * HP + k4 * 4] = h;
        }
        __syncthreads();
        // inner: 8 pairs x 8 outs register tile, k-chunk of 32
#pragma unroll
        for (int k4 = 0; k4 < 8; ++k4) {
            float4 h4[8];
#pragma unroll
            for (int pp = 0; pp < 8; ++pp)
                h4[pp] = *(const float4*)&hsh[(pg * 8 + pp) * HP + k4 * 4];
#pragma unroll
            for (int kk = 0; kk < 4; ++kk) {
                const float* wrow = &W2sh[(k4 * 4 + kk) * WP + obase];
                float4 w0 = *(const float4*)&wrow[0];
                float4 w1 = *(const float4*)&wrow[4];
#pragma unroll
                for (int pp = 0; pp < 8; ++pp) {
                    float hv = (kk == 0) ? h4[pp].x : (kk == 1) ? h4[pp].y
                             : (kk == 2) ? h4[pp].z : h4[pp].w;
                    acc[pp][0] += hv * w0.x; acc[pp][1] += hv * w0.y;
                    acc[pp][2] += hv * w0.z; acc[pp][3] += hv * w0.w;
                    acc[pp][4] += hv * w1.x; acc[pp][5] += hv * w1.y;
                    acc[pp][6] += hv * w1.z; acc[pp][7] += hv * w1.w;
                }
            }
        }
    }
    __syncthreads();

    // relu(acc + b2) summed over this thread's 8 pairs
    float psum[8];
#pragma unroll
    for (int oo = 0; oo < 8; ++oo) {
        float b2v = b2[obase + oo];
        float s = 0.f;
#pragma unroll
        for (int pp = 0; pp < 8; ++pp) s += fmaxf(acc[pp][oo] + b2v, 0.f);
        psum[oo] = s;
    }
#pragma unroll
    for (int oo = 0; oo < 8; ++oo) redsh[pg * WP + obase + oo] = psum[oo];
    __syncthreads();
    if (t < REL) {
        float s = 0.f;
#pragma unroll
        for (int g = 0; g < 16; ++g) s += redsh[g * WP + t];
        partial[blk * REL + t] = s;
    }
}

// ---------------- kernel R: reduce per-block partials -> R (with 1/N^2 mean scale)
__global__ void kR(const float* __restrict__ partial, float* __restrict__ R) {
    int o = blockIdx.x;          // 0..127
    int t = threadIdx.x;         // 256 threads
    float s = 0.f;
    for (int b = t; b < NBLK; b += 256) s += partial[b * REL + o];
    __shared__ float sh[256];
    sh[t] = s;
    __syncthreads();
    for (int st = 128; st > 0; st >>= 1) {
        if (t < st) sh[t] += sh[t + st];
        __syncthreads();
    }
    if (t == 0) R[o] = sh[0] * (1.f / 262144.f);
}

// ---------------- kernel C: final tiny MLP
__global__ void kC(const float* __restrict__ R, const float* __restrict__ W3,
                   const float* __restrict__ b3, const float* __restrict__ W4,
                   const float* __restrict__ b4, float* __restrict__ out) {
    __shared__ float Rsh[REL];
    __shared__ float t1[ODIM];
    int t = threadIdx.x;         // 128 threads
    Rsh[t] = R[t];
    __syncthreads();
    if (t < ODIM) {
        float s = b3[t];
#pragma unroll 8
        for (int k = 0; k < REL; ++k) s += Rsh[k] * W3[k * ODIM + t];
        t1[t] = fmaxf(s, 0.f);
    }
    __syncthreads();
    if (t < ODIM) {
        float s = b4[t];
#pragma unroll 8
        for (int k = 0; k < ODIM; ++k) s += t1[k] * W4[k * ODIM + t];
        out[t] = s;
    }
}

extern "C" void kernel_launch(void* const* d_in, const int* in_sizes, int n_in,
                              void* d_out, int out_size, void* d_ws, size_t ws_size,
                              hipStream_t stream) {
    const float* X  = (const float*)d_in[0];
    const float* W1 = (const float*)d_in[1];
    const float* b1 = (const float*)d_in[2];
    const float* W2 = (const float*)d_in[3];
    const float* b2 = (const float*)d_in[4];
    const float* W3 = (const float*)d_in[5];
    const float* b3 = (const float*)d_in[6];
    const float* W4 = (const float*)d_in[7];
    const float* b4 = (const float*)d_in[8];
    float* out = (float*)d_out;

    float* ws      = (float*)d_ws;
    float* Apb     = ws;                       // 512*256
    float* Bm      = ws + NN * HID;            // 512*256
    float* partial = ws + 2 * NN * HID;        // 2048*128
    float* R       = partial + NBLK * REL;     // 128

    kA<<<NN, 256, 0, stream>>>(X, W1, b1, Apb, Bm);
    kB<<<NBLK, 256, 0, stream>>>(Apb, Bm, W2, b2, partial);
    kR<<<REL, 256, 0, stream>>>(partial, R);
    kC<<<1, 128, 0, stream>>>(R, W3, b3, W4, b4, out);
}

// Round 2
// 60.152 us; speedup vs baseline: 3.3553x; 3.3553x over previous
//
#include <hip/hip_runtime.h>
#include <hip/hip_bf16.h>

#define NN   512
#define D    128      // INPUT_DIM
#define HID  256      // HIDDEN_DIM
#define REL  128      // REL_DIM
#define ODIM 64
#define NBLK 2048     // (512/8)*(512/16) pair-tiles

typedef __attribute__((ext_vector_type(4))) float        f32x4;
typedef __attribute__((ext_vector_type(8))) short        s16x8;
typedef __attribute__((ext_vector_type(4))) unsigned int u32x4;

union BF8 { u32x4 u4; s16x8 s8; unsigned int u[4]; };

__device__ __forceinline__ float bflo(unsigned int u) { return __builtin_bit_cast(float, u << 16); }
__device__ __forceinline__ float bfhi(unsigned int u) { return __builtin_bit_cast(float, u & 0xffff0000u); }
__device__ __forceinline__ unsigned int pk2(float lo, float hi) {
    float2 f = make_float2(lo, hi);
    __hip_bfloat162 b = __float22bfloat162_rn(f);
    union { __hip_bfloat162 v; unsigned int u; } c; c.v = b; return c.u;
}
__device__ __forceinline__ unsigned short bfbits(float f) {
    __hip_bfloat16 h = __float2bfloat16(f);
    union { __hip_bfloat16 h; unsigned short u; } c; c.h = h; return c.u;
}

// ---------------- kA: A'[i][c] = x_i @ W1_top[:,c] + b1[c] (f32); Bbf[i][c] = bf16(x_i @ W1_bot[:,c])
__global__ void kA(const float* __restrict__ X, const float* __restrict__ W1,
                   const float* __restrict__ b1, float* __restrict__ Apb,
                   unsigned short* __restrict__ Bbf) {
    __shared__ float Xs[4][D];
    int r0 = blockIdx.x * 4;
    int t  = threadIdx.x;           // 0..255
#pragma unroll
    for (int q = 0; q < 2; ++q) {
        int idx = q * 256 + t;
        Xs[idx >> 7][idx & 127] = X[(r0 + (idx >> 7)) * D + (idx & 127)];
    }
    __syncthreads();
    float a[4], b[4];
    float b1c = b1[t];
#pragma unroll
    for (int r = 0; r < 4; ++r) { a[r] = b1c; b[r] = 0.f; }
#pragma unroll 4
    for (int k = 0; k < D; ++k) {
        float wt = W1[k * HID + t];
        float wb = W1[(D + k) * HID + t];
#pragma unroll
        for (int r = 0; r < 4; ++r) {
            a[r] += Xs[r][k] * wt;
            b[r] += Xs[r][k] * wb;
        }
    }
#pragma unroll
    for (int r = 0; r < 4; ++r) {
        Apb[(r0 + r) * HID + t] = a[r];
        Bbf[(r0 + r) * HID + t] = bfbits(b[r]);
    }
}

// ---------------- kW: pre-pack W2 (f32 [256][128]) into bf16 MFMA B-fragment order.
// W2f[((s*8+cf)*64 + l)*8 + e] = bf16( W2[s*32 + 8*(l>>4) + e][cf*16 + (l&15)] )
__global__ void kW(const float* __restrict__ W2, unsigned short* __restrict__ W2f) {
    int gid = blockIdx.x * 256 + threadIdx.x;   // 0..4095
    if (gid >= 4096) return;
    int s  = gid >> 9;
    int cf = (gid >> 6) & 7;
    int l  = gid & 63;
    int kb = s * 32 + 8 * (l >> 4);
    int c  = cf * 16 + (l & 15);
    unsigned short v[8];
#pragma unroll
    for (int e = 0; e < 8; ++e) v[e] = bfbits(W2[(kb + e) * REL + c]);
    u32x4 pkd;
#pragma unroll
    for (int d = 0; d < 4; ++d) pkd[d] = (unsigned int)v[2 * d] | ((unsigned int)v[2 * d + 1] << 16);
    *(u32x4*)&W2f[(size_t)gid * 8] = pkd;
}

// ---------------- kB: MFMA pair GEMM. 2048 blocks x 256 thr (4 waves).
// Pair tile 8i x 16j = 128 pairs; wave w owns cols [w*32, w*32+32).
__global__ __launch_bounds__(256, 2) void kB(const float* __restrict__ Apb,
                                             const unsigned short* __restrict__ Bbf,
                                             const unsigned short* __restrict__ W2f,
                                             const float* __restrict__ b2,
                                             float* __restrict__ partial) {
    __shared__ float          Ash[8][264];   // A' rows (f32), 16B-aligned stride
    __shared__ unsigned short Bsh[16][264];  // B rows (bf16)

    int t   = threadIdx.x;
    int w   = t >> 6;
    int l   = t & 63;
    int blk = blockIdx.x;
    int i0  = (blk >> 5) * 8;
    int j0  = (blk & 31) * 16;
    int c0  = w * 32;
    int kg  = l >> 4;      // k-group 0..3
    int jl  = l & 15;

    // W2 fragments for this wave's 32 cols: 16 frags (8 k-steps x 2 col-frags), 64 VGPR
    BF8 w2r[16];
#pragma unroll
    for (int s = 0; s < 8; ++s)
#pragma unroll
        for (int n = 0; n < 2; ++n)
            w2r[2 * s + n].u4 = *(const u32x4*)&W2f[(size_t)((s * 8 + (w * 2 + n)) * 64 + l) * 8];

    // stage A' (8x256 f32) and B (16x256 bf16)
#pragma unroll
    for (int q = 0; q < 2; ++q) {
        int idx = q * 256 + t;
        int r = idx >> 6, c4 = idx & 63;
        *(f32x4*)&Ash[r][c4 * 4] = *(const f32x4*)&Apb[(i0 + r) * HID + c4 * 4];
    }
#pragma unroll
    for (int q = 0; q < 2; ++q) {
        int idx = q * 256 + t;
        int r = idx >> 5, c8 = idx & 31;
        *(u32x4*)&Bsh[r][c8 * 8] = *(const u32x4*)&Bbf[(j0 + r) * HID + c8 * 8];
    }
    __syncthreads();

    // preload this lane's B-row slice: B[j0+jl][s*32 + kg*8 + e] for s=0..7 (64 bf16, 32 VGPR)
    BF8 brow[8];
#pragma unroll
    for (int s = 0; s < 8; ++s) brow[s].u4 = *(const u32x4*)&Bsh[jl][s * 32 + kg * 8];

    f32x4 acc[8][2];
#pragma unroll
    for (int pf = 0; pf < 8; ++pf)
#pragma unroll
        for (int n = 0; n < 2; ++n) acc[pf][n] = (f32x4){0.f, 0.f, 0.f, 0.f};

#pragma unroll
    for (int s = 0; s < 8; ++s) {
        float bv[8];
#pragma unroll
        for (int d = 0; d < 4; ++d) {
            unsigned int u = brow[s].u[d];
            bv[2 * d]     = bflo(u);
            bv[2 * d + 1] = bfhi(u);
        }
#pragma unroll
        for (int pf = 0; pf < 8; ++pf) {
            const float* ap = &Ash[pf][s * 32 + kg * 8];
            f32x4 a0 = *(const f32x4*)ap;
            f32x4 a1 = *(const f32x4*)(ap + 4);
            BF8 af;
            af.u[0] = pk2(fmaxf(a0.x + bv[0], 0.f), fmaxf(a0.y + bv[1], 0.f));
            af.u[1] = pk2(fmaxf(a0.z + bv[2], 0.f), fmaxf(a0.w + bv[3], 0.f));
            af.u[2] = pk2(fmaxf(a1.x + bv[4], 0.f), fmaxf(a1.y + bv[5], 0.f));
            af.u[3] = pk2(fmaxf(a1.z + bv[6], 0.f), fmaxf(a1.w + bv[7], 0.f));
            acc[pf][0] = __builtin_amdgcn_mfma_f32_16x16x32_bf16(af.s8, w2r[2 * s + 0].s8, acc[pf][0], 0, 0, 0);
            acc[pf][1] = __builtin_amdgcn_mfma_f32_16x16x32_bf16(af.s8, w2r[2 * s + 1].s8, acc[pf][1], 0, 0, 0);
        }
    }

    // epilogue: relu(acc + b2) summed over this block's 128 pairs, per column
    float b2v0 = b2[c0 + jl];
    float b2v1 = b2[c0 + 16 + jl];
    float s0 = 0.f, s1 = 0.f;
#pragma unroll
    for (int pf = 0; pf < 8; ++pf)
#pragma unroll
        for (int r = 0; r < 4; ++r) {
            s0 += fmaxf(acc[pf][0][r] + b2v0, 0.f);
            s1 += fmaxf(acc[pf][1][r] + b2v1, 0.f);
        }
    s0 += __shfl_xor(s0, 16); s0 += __shfl_xor(s0, 32);
    s1 += __shfl_xor(s1, 16); s1 += __shfl_xor(s1, 32);
    if (l < 16) {
        partial[blk * REL + c0 + l]      = s0;
        partial[blk * REL + c0 + 16 + l] = s1;
    }
}

// ---------------- kR: reduce partials -> R (mean)
__global__ void kR(const float* __restrict__ partial, float* __restrict__ R) {
    int o = blockIdx.x;
    int t = threadIdx.x;
    float s = 0.f;
    for (int b = t; b < NBLK; b += 256) s += partial[b * REL + o];
    __shared__ float sh[256];
    sh[t] = s;
    __syncthreads();
    for (int st = 128; st > 0; st >>= 1) {
        if (t < st) sh[t] += sh[t + st];
        __syncthreads();
    }
    if (t == 0) R[o] = sh[0] * (1.f / 262144.f);
}

// ---------------- kC: final tiny MLP
__global__ void kC(const float* __restrict__ R, const float* __restrict__ W3,
                   const float* __restrict__ b3, const float* __restrict__ W4,
                   const float* __restrict__ b4, float* __restrict__ out) {
    __shared__ float Rsh[REL];
    __shared__ float t1[ODIM];
    int t = threadIdx.x;   // 128 threads
    Rsh[t] = R[t];
    __syncthreads();
    if (t < ODIM) {
        float s = b3[t];
#pragma unroll 8
        for (int k = 0; k < REL; ++k) s += Rsh[k] * W3[k * ODIM + t];
        t1[t] = fmaxf(s, 0.f);
    }
    __syncthreads();
    if (t < ODIM) {
        float s = b4[t];
#pragma unroll 8
        for (int k = 0; k < ODIM; ++k) s += t1[k] * W4[k * ODIM + t];
        out[t] = s;
    }
}

extern "C" void kernel_launch(void* const* d_in, const int* in_sizes, int n_in,
                              void* d_out, int out_size, void* d_ws, size_t ws_size,
                              hipStream_t stream) {
    const float* X  = (const float*)d_in[0];
    const float* W1 = (const float*)d_in[1];
    const float* b1 = (const float*)d_in[2];
    const float* W2 = (const float*)d_in[3];
    const float* b2 = (const float*)d_in[4];
    const float* W3 = (const float*)d_in[5];
    const float* b3 = (const float*)d_in[6];
    const float* W4 = (const float*)d_in[7];
    const float* b4 = (const float*)d_in[8];
    float* out = (float*)d_out;

    char* ws = (char*)d_ws;
    float*          Apb     = (float*)ws;                         // 512*256 f32   = 512 KB
    unsigned short* Bbf     = (unsigned short*)(ws + 524288);     // 512*256 bf16  = 256 KB
    unsigned short* W2f     = (unsigned short*)(ws + 786432);     // 256*128 bf16  =  64 KB
    float*          partial = (float*)(ws + 851968);              // 2048*128 f32  =   1 MB
    float*          R       = (float*)(ws + 1900544);             // 128 f32

    kA<<<128, 256, 0, stream>>>(X, W1, b1, Apb, Bbf);
    kW<<<16, 256, 0, stream>>>(W2, W2f);
    kB<<<NBLK, 256, 0, stream>>>(Apb, Bbf, W2f, b2, partial);
    kR<<<REL, 256, 0, stream>>>(partial, R);
    kC<<<1, 128, 0, stream>>>(R, W3, b3, W4, b4, out);
}

// Round 4
// 42.268 us; speedup vs baseline: 4.7751x; 1.4231x over previous
//
#include <hip/hip_runtime.h>
#include <hip/hip_fp16.h>

#define NN   512
#define D    128      // INPUT_DIM
#define HID  256      // HIDDEN_DIM
#define REL  128      // REL_DIM
#define ODIM 64
#define NBLK 2048     // (512/8)*(512/16) pair-tiles

typedef __attribute__((ext_vector_type(4))) float        f32x4;
typedef __attribute__((ext_vector_type(8))) _Float16     f16x8;
typedef __attribute__((ext_vector_type(4))) unsigned int u32x4;

union H8 { u32x4 u4; f16x8 h8; unsigned int u[4]; };

// ---------------- kA: A'[i][c] = fp16(x_i @ W1_top[:,c] + b1[c]); Bh[i][c] = fp16(x_i @ W1_bot[:,c])
__global__ void kA(const float* __restrict__ X, const float* __restrict__ W1,
                   const float* __restrict__ b1, _Float16* __restrict__ Aph,
                   _Float16* __restrict__ Bh) {
    __shared__ float Xs[4][D];
    int r0 = blockIdx.x * 4;
    int t  = threadIdx.x;           // 0..255
#pragma unroll
    for (int q = 0; q < 2; ++q) {
        int idx = q * 256 + t;
        Xs[idx >> 7][idx & 127] = X[(r0 + (idx >> 7)) * D + (idx & 127)];
    }
    __syncthreads();
    float a[4], b[4];
    float b1c = b1[t];
#pragma unroll
    for (int r = 0; r < 4; ++r) { a[r] = b1c; b[r] = 0.f; }
#pragma unroll 4
    for (int k = 0; k < D; ++k) {
        float wt = W1[k * HID + t];
        float wb = W1[(D + k) * HID + t];
#pragma unroll
        for (int r = 0; r < 4; ++r) {
            a[r] += Xs[r][k] * wt;
            b[r] += Xs[r][k] * wb;
        }
    }
#pragma unroll
    for (int r = 0; r < 4; ++r) {
        Aph[(r0 + r) * HID + t] = (_Float16)a[r];
        Bh[(r0 + r) * HID + t]  = (_Float16)b[r];
    }
}

// ---------------- kW: pre-pack W2 (f32 [256][128]) into fp16 MFMA B-fragment order.
// W2f[((s*8+cf)*64 + l)*8 + e] = fp16( W2[s*32 + 8*(l>>4) + e][cf*16 + (l&15)] )
__global__ void kW(const float* __restrict__ W2, _Float16* __restrict__ W2f) {
    int gid = blockIdx.x * 256 + threadIdx.x;   // 0..4095
    if (gid >= 4096) return;
    int s  = gid >> 9;
    int cf = (gid >> 6) & 7;
    int l  = gid & 63;
    int kb = s * 32 + 8 * (l >> 4);
    int c  = cf * 16 + (l & 15);
    H8 pkd;
#pragma unroll
    for (int e = 0; e < 8; ++e) pkd.h8[e] = (_Float16)W2[(kb + e) * REL + c];
    *(u32x4*)&W2f[(size_t)gid * 8] = pkd.u4;
}

// ---------------- kB: MFMA pair GEMM, fp16 operands. 2048 blocks x 256 thr (4 waves).
// Pair tile 8i x 16j = 128 pairs; wave w owns cols [w*32, w*32+32).
__global__ __launch_bounds__(256, 2) void kB(const _Float16* __restrict__ Aph,
                                             const _Float16* __restrict__ Bh,
                                             const _Float16* __restrict__ W2f,
                                             const float* __restrict__ b2,
                                             float* __restrict__ partial) {
    __shared__ _Float16 Ash[8][264];   // A' rows (fp16), stride 528 B (16B-aligned)
    __shared__ _Float16 Bsh[16][264];  // B rows (fp16)

    int t   = threadIdx.x;
    int w   = t >> 6;
    int l   = t & 63;
    int blk = blockIdx.x;
    int i0  = (blk >> 5) * 8;
    int j0  = (blk & 31) * 16;
    int c0  = w * 32;
    int kg  = l >> 4;      // k-group 0..3
    int jl  = l & 15;

    // W2 fragments for this wave's 32 cols: 16 frags (8 k-steps x 2 col-frags), 64 VGPR
    H8 w2r[16];
#pragma unroll
    for (int s = 0; s < 8; ++s)
#pragma unroll
        for (int n = 0; n < 2; ++n)
            w2r[2 * s + n].u4 = *(const u32x4*)&W2f[(size_t)((s * 8 + (w * 2 + n)) * 64 + l) * 8];

    // stage A' (8x256 fp16 = 256 16B-chunks) and B (16x256 fp16 = 512 chunks)
    {
        int r = t >> 5, c8 = t & 31;
        *(u32x4*)&Ash[r][c8 * 8] = *(const u32x4*)&Aph[(i0 + r) * HID + c8 * 8];
    }
#pragma unroll
    for (int q = 0; q < 2; ++q) {
        int idx = q * 256 + t;
        int r = idx >> 5, c8 = idx & 31;
        *(u32x4*)&Bsh[r][c8 * 8] = *(const u32x4*)&Bh[(j0 + r) * HID + c8 * 8];
    }
    __syncthreads();

    // preload this lane's B-row slice: B[j0+jl][s*32 + kg*8 + e], s=0..7 (64 fp16, 32 VGPR)
    H8 brow[8];
#pragma unroll
    for (int s = 0; s < 8; ++s) brow[s].u4 = *(const u32x4*)&Bsh[jl][s * 32 + kg * 8];

    f32x4 acc[8][2];
#pragma unroll
    for (int pf = 0; pf < 8; ++pf)
#pragma unroll
        for (int n = 0; n < 2; ++n) acc[pf][n] = (f32x4){0.f, 0.f, 0.f, 0.f};

    const f16x8 zero8 = (f16x8)(_Float16)0.f;

#pragma unroll
    for (int s = 0; s < 8; ++s) {
#pragma unroll
        for (int pf = 0; pf < 8; ++pf) {
            H8 a = *(const H8*)&Ash[pf][s * 32 + kg * 8];   // 4-way broadcast read
            H8 af;
            f16x8 sum = a.h8 + brow[s].h8;                  // v_pk_add_f16 x4
            af.h8 = __builtin_elementwise_max(sum, zero8);  // v_pk_max_f16 x4
            acc[pf][0] = __builtin_amdgcn_mfma_f32_16x16x32_f16(af.h8, w2r[2 * s + 0].h8, acc[pf][0], 0, 0, 0);
            acc[pf][1] = __builtin_amdgcn_mfma_f32_16x16x32_f16(af.h8, w2r[2 * s + 1].h8, acc[pf][1], 0, 0, 0);
        }
    }

    // epilogue: relu(acc + b2) summed over this block's 128 pairs, per column
    float b2v0 = b2[c0 + jl];
    float b2v1 = b2[c0 + 16 + jl];
    float s0 = 0.f, s1 = 0.f;
#pragma unroll
    for (int pf = 0; pf < 8; ++pf)
#pragma unroll
        for (int r = 0; r < 4; ++r) {
            s0 += fmaxf(acc[pf][0][r] + b2v0, 0.f);
            s1 += fmaxf(acc[pf][1][r] + b2v1, 0.f);
        }
    s0 += __shfl_xor(s0, 16); s0 += __shfl_xor(s0, 32);
    s1 += __shfl_xor(s1, 16); s1 += __shfl_xor(s1, 32);
    if (l < 16) {
        partial[blk * REL + c0 + l]      = s0;
        partial[blk * REL + c0 + 16 + l] = s1;
    }
}

// ---------------- kR: reduce partials -> R (mean)
__global__ void kR(const float* __restrict__ partial, float* __restrict__ R) {
    int o = blockIdx.x;
    int t = threadIdx.x;
    float s = 0.f;
    for (int b = t; b < NBLK; b += 256) s += partial[b * REL + o];
    __shared__ float sh[256];
    sh[t] = s;
    __syncthreads();
    for (int st = 128; st > 0; st >>= 1) {
        if (t < st) sh[t] += sh[t + st];
        __syncthreads();
    }
    if (t == 0) R[o] = sh[0] * (1.f / 262144.f);
}

// ---------------- kC: final tiny MLP
__global__ void kC(const float* __restrict__ R, const float* __restrict__ W3,
                   const float* __restrict__ b3, const float* __restrict__ W4,
                   const float* __restrict__ b4, float* __restrict__ out) {
    __shared__ float Rsh[REL];
    __shared__ float t1[ODIM];
    int t = threadIdx.x;   // 128 threads
    Rsh[t] = R[t];
    __syncthreads();
    if (t < ODIM) {
        float s = b3[t];
#pragma unroll 8
        for (int k = 0; k < REL; ++k) s += Rsh[k] * W3[k * ODIM + t];
        t1[t] = fmaxf(s, 0.f);
    }
    __syncthreads();
    if (t < ODIM) {
        float s = b4[t];
#pragma unroll 8
        for (int k = 0; k < ODIM; ++k) s += t1[k] * W4[k * ODIM + t];
        out[t] = s;
    }
}

extern "C" void kernel_launch(void* const* d_in, const int* in_sizes, int n_in,
                              void* d_out, int out_size, void* d_ws, size_t ws_size,
                              hipStream_t stream) {
    const float* X  = (const float*)d_in[0];
    const float* W1 = (const float*)d_in[1];
    const float* b1 = (const float*)d_in[2];
    const float* W2 = (const float*)d_in[3];
    const float* b2 = (const float*)d_in[4];
    const float* W3 = (const float*)d_in[5];
    const float* b3 = (const float*)d_in[6];
    const float* W4 = (const float*)d_in[7];
    const float* b4 = (const float*)d_in[8];
    float* out = (float*)d_out;

    char* ws = (char*)d_ws;
    _Float16* Aph     = (_Float16*)ws;                 // 512*256 fp16 = 256 KB
    _Float16* Bh      = (_Float16*)(ws + 262144);      // 512*256 fp16 = 256 KB
    _Float16* W2f     = (_Float16*)(ws + 524288);      // 256*128 fp16 =  64 KB
    float*    partial = (float*)(ws + 589824);         // 2048*128 f32 =   1 MB
    float*    R       = (float*)(ws + 1638400);        // 128 f32

    kA<<<128, 256, 0, stream>>>(X, W1, b1, Aph, Bh);
    kW<<<16, 256, 0, stream>>>(W2, W2f);
    kB<<<NBLK, 256, 0, stream>>>(Aph, Bh, W2f, b2, partial);
    kR<<<REL, 256, 0, stream>>>(partial, R);
    kC<<<1, 128, 0, stream>>>(R, W3, b3, W4, b4, out);
}

// Round 5
// 40.932 us; speedup vs baseline: 4.9309x; 1.0326x over previous
//
#include <hip/hip_runtime.h>
#include <hip/hip_fp16.h>

#define NN   512
#define D    128      // INPUT_DIM
#define HID  256      // HIDDEN_DIM
#define REL  128      // REL_DIM
#define ODIM 64
#define NBLK 2048     // (512/8)*(512/16) pair-tiles

typedef __attribute__((ext_vector_type(4))) float        f32x4;
typedef __attribute__((ext_vector_type(8))) _Float16     f16x8;
typedef __attribute__((ext_vector_type(4))) unsigned int u32x4;

union H8 { u32x4 u4; f16x8 h8; unsigned int u[4]; };

// ---------------- kAW: blocks 0..127 -> kA (A'/B precompute); blocks 128..143 -> kW (W2 pack)
// kA: A'[i][c] = fp16(x_i @ W1_top[:,c] + b1[c]); Bh[i][c] = fp16(x_i @ W1_bot[:,c])
// kW: W2f[((s*8+cf)*64 + l)*8 + e] = fp16( W2[s*32 + 8*(l>>4) + e][cf*16 + (l&15)] )
__global__ void kAW(const float* __restrict__ X, const float* __restrict__ W1,
                    const float* __restrict__ b1, _Float16* __restrict__ Aph,
                    _Float16* __restrict__ Bh,
                    const float* __restrict__ W2, _Float16* __restrict__ W2f) {
    __shared__ float Xs[4][D];
    int t = threadIdx.x;            // 0..255
    if (blockIdx.x >= 128) {
        int gid = (blockIdx.x - 128) * 256 + t;   // 0..4095
        int s  = gid >> 9;
        int cf = (gid >> 6) & 7;
        int l  = gid & 63;
        int kb = s * 32 + 8 * (l >> 4);
        int c  = cf * 16 + (l & 15);
        H8 pkd;
#pragma unroll
        for (int e = 0; e < 8; ++e) pkd.h8[e] = (_Float16)W2[(kb + e) * REL + c];
        *(u32x4*)&W2f[(size_t)gid * 8] = pkd.u4;
        return;
    }
    int r0 = blockIdx.x * 4;
#pragma unroll
    for (int q = 0; q < 2; ++q) {
        int idx = q * 256 + t;
        Xs[idx >> 7][idx & 127] = X[(r0 + (idx >> 7)) * D + (idx & 127)];
    }
    __syncthreads();
    float a[4], b[4];
    float b1c = b1[t];
#pragma unroll
    for (int r = 0; r < 4; ++r) { a[r] = b1c; b[r] = 0.f; }
#pragma unroll 4
    for (int k = 0; k < D; ++k) {
        float wt = W1[k * HID + t];
        float wb = W1[(D + k) * HID + t];
#pragma unroll
        for (int r = 0; r < 4; ++r) {
            a[r] += Xs[r][k] * wt;
            b[r] += Xs[r][k] * wb;
        }
    }
#pragma unroll
    for (int r = 0; r < 4; ++r) {
        Aph[(r0 + r) * HID + t] = (_Float16)a[r];
        Bh[(r0 + r) * HID + t]  = (_Float16)b[r];
    }
}

// ---------------- kB: MFMA pair GEMM, fp16 operands. 2048 blocks x 256 thr (4 waves).
// Pair tile 8i x 16j = 128 pairs; wave w owns cols [w*32, w*32+32).
// Software-pipelined: A-broadcast reads for step s+1 issued before MFMA cluster of step s.
__global__ __launch_bounds__(256, 3) void kB(const _Float16* __restrict__ Aph,
                                             const _Float16* __restrict__ Bh,
                                             const _Float16* __restrict__ W2f,
                                             const float* __restrict__ b2,
                                             float* __restrict__ partial) {
    __shared__ _Float16 Ash[8][264];   // A' rows (fp16), stride 528 B (16B-aligned)
    __shared__ _Float16 Bsh[16][264];  // B rows (fp16)

    int t   = threadIdx.x;
    int w   = t >> 6;
    int l   = t & 63;
    int blk = blockIdx.x;
    int i0  = (blk >> 5) * 8;
    int j0  = (blk & 31) * 16;
    int c0  = w * 32;
    int kg  = l >> 4;      // k-group 0..3
    int jl  = l & 15;

    // W2 fragments for this wave's 32 cols: 16 frags (8 k-steps x 2 col-frags), 64 VGPR
    H8 w2r[16];
#pragma unroll
    for (int s = 0; s < 8; ++s)
#pragma unroll
        for (int n = 0; n < 2; ++n)
            w2r[2 * s + n].u4 = *(const u32x4*)&W2f[(size_t)((s * 8 + (w * 2 + n)) * 64 + l) * 8];

    // stage A' (8x256 fp16 = 256 16B-chunks) and B (16x256 fp16 = 512 chunks)
    {
        int r = t >> 5, c8 = t & 31;
        *(u32x4*)&Ash[r][c8 * 8] = *(const u32x4*)&Aph[(i0 + r) * HID + c8 * 8];
    }
#pragma unroll
    for (int q = 0; q < 2; ++q) {
        int idx = q * 256 + t;
        int r = idx >> 5, c8 = idx & 31;
        *(u32x4*)&Bsh[r][c8 * 8] = *(const u32x4*)&Bh[(j0 + r) * HID + c8 * 8];
    }
    __syncthreads();

    // preload this lane's B-row slice: B[j0+jl][s*32 + kg*8 + e], s=0..7 (64 fp16, 32 VGPR)
    H8 brow[8];
#pragma unroll
    for (int s = 0; s < 8; ++s) brow[s].u4 = *(const u32x4*)&Bsh[jl][s * 32 + kg * 8];

    f32x4 acc[8][2];
#pragma unroll
    for (int pf = 0; pf < 8; ++pf)
#pragma unroll
        for (int n = 0; n < 2; ++n) acc[pf][n] = (f32x4){0.f, 0.f, 0.f, 0.f};

    const f16x8 zero8 = (f16x8)(_Float16)0.f;

    // pipelined main loop: prefetch s+1 A-broadcasts before computing step s
    H8 ac[8], an[8];
#pragma unroll
    for (int pf = 0; pf < 8; ++pf)
        ac[pf] = *(const H8*)&Ash[pf][kg * 8];           // s = 0 fragments

#pragma unroll
    for (int s = 0; s < 8; ++s) {
        if (s < 7) {
#pragma unroll
            for (int pf = 0; pf < 8; ++pf)
                an[pf] = *(const H8*)&Ash[pf][(s + 1) * 32 + kg * 8];
        }
#pragma unroll
        for (int pf = 0; pf < 8; ++pf) {
            f16x8 sum = ac[pf].h8 + brow[s].h8;             // v_pk_add_f16 x4
            H8 af;
            af.h8 = __builtin_elementwise_max(sum, zero8);  // v_pk_max_f16 x4
            acc[pf][0] = __builtin_amdgcn_mfma_f32_16x16x32_f16(af.h8, w2r[2 * s + 0].h8, acc[pf][0], 0, 0, 0);
            acc[pf][1] = __builtin_amdgcn_mfma_f32_16x16x32_f16(af.h8, w2r[2 * s + 1].h8, acc[pf][1], 0, 0, 0);
        }
#pragma unroll
        for (int pf = 0; pf < 8; ++pf) ac[pf] = an[pf];
    }

    // epilogue: relu(acc + b2) summed over this block's 128 pairs, per column
    float b2v0 = b2[c0 + jl];
    float b2v1 = b2[c0 + 16 + jl];
    float s0 = 0.f, s1 = 0.f;
#pragma unroll
    for (int pf = 0; pf < 8; ++pf)
#pragma unroll
        for (int r = 0; r < 4; ++r) {
            s0 += fmaxf(acc[pf][0][r] + b2v0, 0.f);
            s1 += fmaxf(acc[pf][1][r] + b2v1, 0.f);
        }
    s0 += __shfl_xor(s0, 16); s0 += __shfl_xor(s0, 32);
    s1 += __shfl_xor(s1, 16); s1 += __shfl_xor(s1, 32);
    if (l < 16) {
        partial[blk * REL + c0 + l]      = s0;
        partial[blk * REL + c0 + 16 + l] = s1;
    }
}

// ---------------- kR: reduce partials -> R (mean)
__global__ void kR(const float* __restrict__ partial, float* __restrict__ R) {
    int o = blockIdx.x;
    int t = threadIdx.x;
    float s = 0.f;
    for (int b = t; b < NBLK; b += 256) s += partial[b * REL + o];
    __shared__ float sh[256];
    sh[t] = s;
    __syncthreads();
    for (int st = 128; st > 0; st >>= 1) {
        if (t < st) sh[t] += sh[t + st];
        __syncthreads();
    }
    if (t == 0) R[o] = sh[0] * (1.f / 262144.f);
}

// ---------------- kC: final tiny MLP
__global__ void kC(const float* __restrict__ R, const float* __restrict__ W3,
                   const float* __restrict__ b3, const float* __restrict__ W4,
                   const float* __restrict__ b4, float* __restrict__ out) {
    __shared__ float Rsh[REL];
    __shared__ float t1[ODIM];
    int t = threadIdx.x;   // 128 threads
    Rsh[t] = R[t];
    __syncthreads();
    if (t < ODIM) {
        float s = b3[t];
#pragma unroll 8
        for (int k = 0; k < REL; ++k) s += Rsh[k] * W3[k * ODIM + t];
        t1[t] = fmaxf(s, 0.f);
    }
    __syncthreads();
    if (t < ODIM) {
        float s = b4[t];
#pragma unroll 8
        for (int k = 0; k < ODIM; ++k) s += t1[k] * W4[k * ODIM + t];
        out[t] = s;
    }
}

extern "C" void kernel_launch(void* const* d_in, const int* in_sizes, int n_in,
                              void* d_out, int out_size, void* d_ws, size_t ws_size,
                              hipStream_t stream) {
    const float* X  = (const float*)d_in[0];
    const float* W1 = (const float*)d_in[1];
    const float* b1 = (const float*)d_in[2];
    const float* W2 = (const float*)d_in[3];
    const float* b2 = (const float*)d_in[4];
    const float* W3 = (const float*)d_in[5];
    const float* b3 = (const float*)d_in[6];
    const float* W4 = (const float*)d_in[7];
    const float* b4 = (const float*)d_in[8];
    float* out = (float*)d_out;

    char* ws = (char*)d_ws;
    _Float16* Aph     = (_Float16*)ws;                 // 512*256 fp16 = 256 KB
    _Float16* Bh      = (_Float16*)(ws + 262144);      // 512*256 fp16 = 256 KB
    _Float16* W2f     = (_Float16*)(ws + 524288);      // 256*128 fp16 =  64 KB
    float*    partial = (float*)(ws + 589824);         // 2048*128 f32 =   1 MB
    float*    R       = (float*)(ws + 1638400);        // 128 f32

    kAW<<<144, 256, 0, stream>>>(X, W1, b1, Aph, Bh, W2, W2f);
    kB<<<NBLK, 256, 0, stream>>>(Aph, Bh, W2f, b2, partial);
    kR<<<REL, 256, 0, stream>>>(partial, R);
    kC<<<1, 128, 0, stream>>>(R, W3, b3, W4, b4, out);
}